// Round 16
// baseline (484.383 us; speedup 1.0000x reference)
//
#include <hip/hip_runtime.h>
#include <cstdint>
#include <cstddef>

typedef unsigned short u16;
typedef __attribute__((ext_vector_type(8))) short bf16x8;
typedef __attribute__((ext_vector_type(4))) float f32x4;

#define MFMA16(a, b, c) __builtin_amdgcn_mfma_f32_16x16x32_bf16((a), (b), (c), 0, 0, 0)

__device__ __forceinline__ u16 f2bf(float f) {
  uint32_t u = __builtin_bit_cast(uint32_t, f);
  u += 0x7fffu + ((u >> 16) & 1u);
  return (u16)(u >> 16);
}
__device__ __forceinline__ float bf2f(u16 h) {
  uint32_t u = ((uint32_t)h) << 16;
  return __builtin_bit_cast(float, u);
}

__device__ __forceinline__ void gload_lds16(const void* g, void* l) {
  __builtin_amdgcn_global_load_lds(
      (const __attribute__((address_space(1))) uint32_t*)g,
      (__attribute__((address_space(3))) uint32_t*)l, 16, 0, 0);
}

// ---------------- LayerNorm (writes bf16 hi [, lo] [, f32]) ----------------
template<bool WRITE_LO, bool WRITE_F32>
__launch_bounds__(256)
__global__ void ln_kernel(const float* __restrict__ in,
                          const float* __restrict__ w, const float* __restrict__ b,
                          u16* __restrict__ out_hi, u16* __restrict__ out_lo,
                          float* __restrict__ out_f32)
{
  int row = blockIdx.x;
  int tid = threadIdx.x;
  const float* x = in + (size_t)row * 1024;
  float4 v = *(const float4*)(x + tid * 4);
  float s  = v.x + v.y + v.z + v.w;
  float s2 = v.x*v.x + v.y*v.y + v.z*v.z + v.w*v.w;
  #pragma unroll
  for (int d = 1; d < 64; d <<= 1) { s += __shfl_xor(s, d); s2 += __shfl_xor(s2, d); }
  __shared__ float red[2][4];
  int wid = tid >> 6;
  if ((tid & 63) == 0) { red[0][wid] = s; red[1][wid] = s2; }
  __syncthreads();
  s  = red[0][0] + red[0][1] + red[0][2] + red[0][3];
  s2 = red[1][0] + red[1][1] + red[1][2] + red[1][3];
  float mean = s * (1.0f / 1024.0f);
  float var  = s2 * (1.0f / 1024.0f) - mean * mean;
  float rstd = rsqrtf(var + 1e-5f);
  float vv[4] = {v.x, v.y, v.z, v.w};
  #pragma unroll
  for (int j = 0; j < 4; ++j) {
    int c = tid * 4 + j;
    float y = (vv[j] - mean) * rstd * w[c] + b[c];
    size_t idx = (size_t)row * 1024 + c;
    u16 hb = f2bf(y);
    out_hi[idx] = hb;
    if (WRITE_LO)  out_lo[idx] = f2bf(y - bf2f(hb));
    if (WRITE_F32) out_f32[idx] = y;
  }
}

// ---------------- f32 -> bf16 hi/lo split (flat) ----------------
__global__ void convert_split_kernel(const float* __restrict__ in,
                                     u16* __restrict__ hi, u16* __restrict__ lo, int n4)
{
  int i = blockIdx.x * blockDim.x + threadIdx.x;
  if (i >= n4) return;
  float4 v = *(const float4*)(in + (size_t)i * 4);
  float a[4] = {v.x, v.y, v.z, v.w};
  u16 hh[4], ll[4];
  #pragma unroll
  for (int j = 0; j < 4; ++j) {
    hh[j] = f2bf(a[j]);
    ll[j] = f2bf(a[j] - bf2f(hh[j]));
  }
  uint2 hp, lp;
  hp.x = (uint32_t)hh[0] | ((uint32_t)hh[1] << 16);
  hp.y = (uint32_t)hh[2] | ((uint32_t)hh[3] << 16);
  lp.x = (uint32_t)ll[0] | ((uint32_t)ll[1] << 16);
  lp.y = (uint32_t)ll[2] | ((uint32_t)ll[3] << 16);
  *(uint2*)(hi + (size_t)i * 4) = hp;
  *(uint2*)(lo + (size_t)i * 4) = lp;
}

// ---------------- transpose + convert f32(R,C) -> bf16(C,R), per expert ----------------
__launch_bounds__(256)
__global__ void transpose_convert_kernel(const float* __restrict__ in, u16* __restrict__ out,
                                         int R, int C)
{
  __shared__ float t[64][65];
  size_t ebase = (size_t)blockIdx.z * R * C;
  int c0 = blockIdx.x * 64, r0 = blockIdx.y * 64;
  int tid = threadIdx.x;
  #pragma unroll
  for (int q = 0; q < 4; ++q) {
    int u = q * 256 + tid;
    int row = u >> 4, col4 = u & 15;
    float4 v = *(const float4*)(in + ebase + (size_t)(r0 + row) * C + c0 + col4 * 4);
    t[row][col4 * 4 + 0] = v.x;
    t[row][col4 * 4 + 1] = v.y;
    t[row][col4 * 4 + 2] = v.z;
    t[row][col4 * 4 + 3] = v.w;
  }
  __syncthreads();
  #pragma unroll
  for (int q = 0; q < 2; ++q) {
    int u = q * 256 + tid;
    int orow = u >> 3, oseg = u & 7;
    u16 tmp[8];
    #pragma unroll
    for (int j = 0; j < 8; ++j)
      tmp[j] = f2bf(t[oseg * 8 + j][orow]);
    *(uint4*)(out + ebase + (size_t)(c0 + orow) * R + r0 + oseg * 8) = *(uint4*)tmp;
  }
}

// ---------------- V transpose within qkv: vT[kvh][d][s] ----------------
__global__ void vtrans_kernel(const u16* __restrict__ qkv, u16* __restrict__ vT)
{
  __shared__ u16 t[32][34];
  int kvh = blockIdx.z;
  int s0 = blockIdx.x * 32, d0 = blockIdx.y * 32;
  int tx = threadIdx.x, ty = threadIdx.y;
  #pragma unroll
  for (int i = 0; i < 4; ++i)
    t[ty + 8*i][tx] = qkv[(size_t)(s0 + ty + 8*i) * 1536 + kvh * 384 + 320 + d0 + tx];
  __syncthreads();
  #pragma unroll
  for (int i = 0; i < 4; ++i)
    vT[((size_t)kvh * 64 + d0 + ty + 8*i) * 2048 + (s0 + tx)] = t[tx][ty + 8*i];
}

// ---------------- GEMM: C[M,N] = A[M,K] * B[N,K]^T  (bf16 MFMA, 2-buf dbuf) --------
// MODE 0: qkv (split in, bf16 hi/lo out)    MODE 1: proj+resid (split in, f32 out)
// MODE 3: fc2 split-K x4 -> bf16 partials, XCD-remap co-locates A/B sharers
// T2 swizzle (rule #21) throughout.
template<int MODE>
__launch_bounds__(256, (MODE < 2) ? 2 : 4)
__global__ void gemm_kernel(const u16* __restrict__ Ahi, const u16* __restrict__ Alo,
                            const u16* __restrict__ Bhi, const u16* __restrict__ Blo,
                            int N, int K,
                            u16* __restrict__ Cb_hi, u16* __restrict__ Cb_lo,
                            float* __restrict__ Cf, const float* __restrict__ resid,
                            const int* __restrict__ tok_of_pair,
                            const int* __restrict__ counts, const int* __restrict__ prefix)
{
  constexpr bool SPLIT = (MODE < 2);
  int bn = blockIdx.x, bm = blockIdx.y;
  int row_base = 0;
  int count = 1 << 30;
  int kbeg = 0, kend = K;
  if constexpr (MODE == 3) {
    int L = blockIdx.x + 32 * (blockIdx.y + 16 * blockIdx.z);
    int xcd = L & 7, idx = L >> 3;
    bn = idx & 7;
    int G = xcd * 64 + (idx >> 3);
    int s = G >> 7;
    int rem = G & 127;
    int e  = rem >> 4;
    bm = rem & 15;
    int kc = K >> 2;
    kbeg = s * kc; kend = kbeg + kc;
    Cb_hi += (size_t)s * 4096 * 1024;
    count = counts[e];
    if (bm * 128 >= count) return;
    row_base = prefix[e];
    Bhi += (size_t)e * N * K;
  }
  __shared__ u16 As[2][SPLIT ? 2 : 1][128 * 32];
  __shared__ u16 Bs[2][SPLIT ? 2 : 1][128 * 32];

  int tid = threadIdx.x;
  int lane = tid & 63;
  int lo16 = lane & 15, hi4 = lane >> 4;
  int wid = tid >> 6, wr = wid >> 1, wc = wid & 1;

  const u16* gA[2][2];
  const u16* gB[2][2];
  int eidx[2];
  #pragma unroll
  for (int q = 0; q < 2; ++q) {
    int el = (q * 256 + tid) * 8;
    int r = el >> 5;
    int kc = ((((el >> 3) & 3) ^ ((r >> 1) & 3)) * 8);
    eidx[q] = el;
    if constexpr (MODE == 3) {
      int lim = count - bm * 128 - 1;
      int lr = r < lim ? r : lim;
      gA[q][0] = Ahi + (size_t)(row_base + bm * 128 + lr) * K + kc;
    } else {
      gA[q][0] = Ahi + (size_t)(bm * 128 + r) * K + kc;
      gA[q][1] = Alo + (size_t)(bm * 128 + r) * K + kc;
    }
    gB[q][0] = Bhi + (size_t)(bn * 128 + r) * K + kc;
    if constexpr (SPLIT) gB[q][1] = Blo + (size_t)(bn * 128 + r) * K + kc;
  }

  auto stage = [&](int buf, int k0) {
    #pragma unroll
    for (int q = 0; q < 2; ++q) {
      gload_lds16(gA[q][0] + k0, &As[buf][0][eidx[q]]);
      gload_lds16(gB[q][0] + k0, &Bs[buf][0][eidx[q]]);
      if constexpr (SPLIT) {
        gload_lds16(gA[q][1] + k0, &As[buf][1][eidx[q]]);
        gload_lds16(gB[q][1] + k0, &Bs[buf][1][eidx[q]]);
      }
    }
  };

  const f32x4 zf = {0.f, 0.f, 0.f, 0.f};
  f32x4 acc[4][4];
  #pragma unroll
  for (int m = 0; m < 4; ++m)
    #pragma unroll
    for (int n = 0; n < 4; ++n) acc[m][n] = zf;

  stage(0, kbeg);
  __syncthreads();

  int csw = ((hi4 ^ ((lo16 >> 1) & 3)) * 8);

  int cur = 0;
  for (int k0 = kbeg; k0 < kend; k0 += 32, cur ^= 1) {
    if (k0 + 32 < kend) stage(cur ^ 1, k0 + 32);

    bf16x8 a0[4], b0[4], a1[4], b1[4];
    #pragma unroll
    for (int m = 0; m < 4; ++m)
      a0[m] = *(const bf16x8*)&As[cur][0][(wr * 64 + m * 16 + lo16) * 32 + csw];
    #pragma unroll
    for (int n = 0; n < 4; ++n)
      b0[n] = *(const bf16x8*)&Bs[cur][0][(wc * 64 + n * 16 + lo16) * 32 + csw];
    if constexpr (SPLIT) {
      #pragma unroll
      for (int m = 0; m < 4; ++m)
        a1[m] = *(const bf16x8*)&As[cur][1][(wr * 64 + m * 16 + lo16) * 32 + csw];
      #pragma unroll
      for (int n = 0; n < 4; ++n)
        b1[n] = *(const bf16x8*)&Bs[cur][1][(wc * 64 + n * 16 + lo16) * 32 + csw];
    }
    #pragma unroll
    for (int m = 0; m < 4; ++m)
      #pragma unroll
      for (int n = 0; n < 4; ++n) {
        acc[m][n] = MFMA16(a0[m], b0[n], acc[m][n]);
        if constexpr (SPLIT) {
          acc[m][n] = MFMA16(a0[m], b1[n], acc[m][n]);
          acc[m][n] = MFMA16(a1[m], b0[n], acc[m][n]);
        }
      }
    __syncthreads();
  }

  #pragma unroll
  for (int m = 0; m < 4; ++m)
    #pragma unroll
    for (int n = 0; n < 4; ++n)
      #pragma unroll
      for (int r = 0; r < 4; ++r) {
        int lr = wr * 64 + m * 16 + hi4 * 4 + r;
        int col = bn * 128 + wc * 64 + n * 16 + lo16;
        float v = acc[m][n][r];
        if constexpr (MODE == 0) {
          size_t idx = (size_t)(bm * 128 + lr) * N + col;
          u16 hb = f2bf(v);
          Cb_hi[idx] = hb;
          Cb_lo[idx] = f2bf(v - bf2f(hb));
        } else if constexpr (MODE == 1) {
          size_t idx = (size_t)(bm * 128 + lr) * N + col;
          Cf[idx] = v + resid[idx];
        } else {
          if (bm * 128 + lr < count) {
            size_t idx = (size_t)(row_base + bm * 128 + lr) * N + col;
            Cb_hi[idx] = f2bf(v);
          }
        }
      }
}

// ---------------- fc1: gathered A, 128x256 tile, gelu -> bf16 act ----------------
// grid (16,16,8): L linear; xcd=L%8 -> e; bn=idx&15 (A-stripe sharers co-XCD); bm=idx>>4.
// 48 KB LDS (A 8K + B 16K per buf), 2 blocks/CU; 32 MFMA per wave per K-step.
__launch_bounds__(256, 2)
__global__ void fc1_kernel(const u16* __restrict__ A, const u16* __restrict__ B,
                           u16* __restrict__ Cb,
                           const int* __restrict__ tok_of_pair,
                           const int* __restrict__ counts, const int* __restrict__ prefix)
{
  const int N = 4096, K = 1024;
  int L = blockIdx.x + 16 * (blockIdx.y + 16 * blockIdx.z);
  int xcd = L & 7, idx = L >> 3;          // idx in [0,256)
  int bn = idx & 15;                      // 16 bn sharing A-stripe: consecutive, same XCD
  int bm = idx >> 4;                      // 0..15
  int e  = xcd;
  int count = counts[e];
  if (bm * 128 >= count) return;
  int row_base = prefix[e];
  B += (size_t)e * (size_t)N * K;

  __shared__ u16 As[2][128 * 32];
  __shared__ u16 Bs[2][256 * 32];

  int tid = threadIdx.x;
  int lane = tid & 63;
  int lo16 = lane & 15, hi4 = lane >> 4;
  int wid = tid >> 6, wr = wid >> 1, wc = wid & 1;

  int lim = count - bm * 128 - 1;
  const u16* gA[2];
  int adst[2];
  #pragma unroll
  for (int q = 0; q < 2; ++q) {
    int c = q * 256 + tid;
    int r = c >> 2;
    int kc = (((c & 3) ^ ((r >> 1) & 3)) * 8);
    adst[q] = c * 8;
    int lr = r < lim ? r : lim;
    int token = tok_of_pair[row_base + bm * 128 + lr];
    gA[q] = A + (size_t)token * K + kc;
  }
  const u16* gB[4];
  int bdst[4];
  #pragma unroll
  for (int q = 0; q < 4; ++q) {
    int c = q * 256 + tid;
    int r = c >> 2;
    int kc = (((c & 3) ^ ((r >> 1) & 3)) * 8);
    bdst[q] = c * 8;
    gB[q] = B + (size_t)(bn * 256 + r) * K + kc;
  }

  auto stage = [&](int buf, int k0) {
    #pragma unroll
    for (int q = 0; q < 2; ++q)
      gload_lds16(gA[q] + k0, &As[buf][adst[q]]);
    #pragma unroll
    for (int q = 0; q < 4; ++q)
      gload_lds16(gB[q] + k0, &Bs[buf][bdst[q]]);
  };

  const f32x4 zf = {0.f, 0.f, 0.f, 0.f};
  f32x4 acc[4][8];
  #pragma unroll
  for (int m = 0; m < 4; ++m)
    #pragma unroll
    for (int n = 0; n < 8; ++n) acc[m][n] = zf;

  stage(0, 0);
  __syncthreads();

  int csw = ((hi4 ^ ((lo16 >> 1) & 3)) * 8);

  int cur = 0;
  for (int k0 = 0; k0 < K; k0 += 32, cur ^= 1) {
    if (k0 + 32 < K) stage(cur ^ 1, k0 + 32);

    bf16x8 a0[4], b0[8];
    #pragma unroll
    for (int m = 0; m < 4; ++m)
      a0[m] = *(const bf16x8*)&As[cur][(wr * 64 + m * 16 + lo16) * 32 + csw];
    #pragma unroll
    for (int n = 0; n < 8; ++n)
      b0[n] = *(const bf16x8*)&Bs[cur][(wc * 128 + n * 16 + lo16) * 32 + csw];
    #pragma unroll
    for (int m = 0; m < 4; ++m)
      #pragma unroll
      for (int n = 0; n < 8; ++n)
        acc[m][n] = MFMA16(a0[m], b0[n], acc[m][n]);
    __syncthreads();
  }

  #pragma unroll
  for (int m = 0; m < 4; ++m)
    #pragma unroll
    for (int n = 0; n < 8; ++n)
      #pragma unroll
      for (int r = 0; r < 4; ++r) {
        int lr = wr * 64 + m * 16 + hi4 * 4 + r;
        if (bm * 128 + lr < count) {
          int col = bn * 256 + wc * 128 + n * 16 + lo16;
          size_t idx = (size_t)(row_base + bm * 128 + lr) * N + col;
          float v = acc[m][n][r];
          float g = 0.5f * v * (1.0f + erff(v * 0.70710678118654752f));
          Cb[idx] = f2bf(g);
        }
      }
}

// ---------------- Flash attention, causal GQA, split-bf16, split-KV balance ----------
struct QState {
  bf16x8 qf[2][2];
  f32x4 o[4];
  float m_r[4], l_r[4];
  int qrow[4];
};

__device__ __forceinline__ void qstate_init(QState& S,
    const u16* qkv_hi, const u16* qkv_lo, int q0w, int qoff, int lo16, int hi4)
{
  const u16* ph = qkv_hi + (size_t)(q0w + lo16) * 1536 + qoff + hi4 * 8;
  const u16* pl = qkv_lo + (size_t)(q0w + lo16) * 1536 + qoff + hi4 * 8;
  S.qf[0][0] = *(const bf16x8*)ph;  S.qf[0][1] = *(const bf16x8*)(ph + 32);
  S.qf[1][0] = *(const bf16x8*)pl;  S.qf[1][1] = *(const bf16x8*)(pl + 32);
  const f32x4 zf = {0.f, 0.f, 0.f, 0.f};
  #pragma unroll
  for (int r = 0; r < 4; ++r) { S.m_r[r] = -INFINITY; S.l_r[r] = 0.f; S.qrow[r] = q0w + hi4 * 4 + r; }
  #pragma unroll
  for (int n = 0; n < 4; ++n) S.o[n] = zf;
}

__device__ __forceinline__ void attn_tile(QState& S, int kv0,
    const u16* Ks0, const u16* Ks1, const u16* Vs0, const u16* Vs1,
    u16* Ps0, u16* Ps1, int lo16, int hi4)
{
  const f32x4 zf = {0.f, 0.f, 0.f, 0.f};
  f32x4 sc[4];
  __builtin_amdgcn_s_setprio(1);
  #pragma unroll
  for (int c2 = 0; c2 < 4; ++c2) {
    sc[c2] = zf;
    int krow = c2 * 16 + lo16;
    const u16* kb  = &Ks0[krow * 64];
    const u16* kbl = &Ks1[krow * 64];
    bf16x8 kh0 = *(const bf16x8*)&kb [((hi4    ) ^ (krow & 7)) * 8];
    bf16x8 kh1 = *(const bf16x8*)&kb [((hi4 + 4) ^ (krow & 7)) * 8];
    bf16x8 kl0 = *(const bf16x8*)&kbl[((hi4    ) ^ (krow & 7)) * 8];
    bf16x8 kl1 = *(const bf16x8*)&kbl[((hi4 + 4) ^ (krow & 7)) * 8];
    sc[c2] = MFMA16(S.qf[0][0], kh0, sc[c2]);
    sc[c2] = MFMA16(S.qf[0][1], kh1, sc[c2]);
    sc[c2] = MFMA16(S.qf[0][0], kl0, sc[c2]);
    sc[c2] = MFMA16(S.qf[0][1], kl1, sc[c2]);
    sc[c2] = MFMA16(S.qf[1][0], kh0, sc[c2]);
    sc[c2] = MFMA16(S.qf[1][1], kh1, sc[c2]);
  }
  __builtin_amdgcn_s_setprio(0);

  float tmax[4] = {-INFINITY, -INFINITY, -INFINITY, -INFINITY};
  #pragma unroll
  for (int c2 = 0; c2 < 4; ++c2) {
    int kv = kv0 + c2 * 16 + lo16;
    #pragma unroll
    for (int r = 0; r < 4; ++r) {
      float sv = sc[c2][r] * 0.125f;
      if (kv > S.qrow[r]) sv = -1e30f;
      sc[c2][r] = sv;
      tmax[r] = fmaxf(tmax[r], sv);
    }
  }
  #pragma unroll
  for (int d = 1; d < 16; d <<= 1)
    #pragma unroll
    for (int r = 0; r < 4; ++r)
      tmax[r] = fmaxf(tmax[r], __shfl_xor(tmax[r], d));
  float rs[4], rowsum[4];
  #pragma unroll
  for (int r = 0; r < 4; ++r) {
    float mn = fmaxf(S.m_r[r], tmax[r]);
    rs[r] = __expf(S.m_r[r] - mn);
    S.m_r[r] = mn;
    rowsum[r] = 0.f;
  }
  #pragma unroll
  for (int c2 = 0; c2 < 4; ++c2)
    #pragma unroll
    for (int r = 0; r < 4; ++r) {
      float pv = __expf(sc[c2][r] - S.m_r[r]);
      sc[c2][r] = pv;
      rowsum[r] += pv;
    }
  #pragma unroll
  for (int d = 1; d < 16; d <<= 1)
    #pragma unroll
    for (int r = 0; r < 4; ++r)
      rowsum[r] += __shfl_xor(rowsum[r], d);
  #pragma unroll
  for (int r = 0; r < 4; ++r) S.l_r[r] = S.l_r[r] * rs[r] + rowsum[r];
  #pragma unroll
  for (int n = 0; n < 4; ++n)
    #pragma unroll
    for (int r = 0; r < 4; ++r) S.o[n][r] *= rs[r];

  #pragma unroll
  for (int c2 = 0; c2 < 4; ++c2)
    #pragma unroll
    for (int r = 0; r < 4; ++r) {
      float pv = sc[c2][r];
      u16 ph = f2bf(pv);
      int pidx = (hi4 * 4 + r) * 72 + c2 * 16 + lo16;
      Ps0[pidx] = ph;
      Ps1[pidx] = f2bf(pv - bf2f(ph));
    }

  __builtin_amdgcn_s_setprio(1);
  #pragma unroll
  for (int k2 = 0; k2 < 2; ++k2) {
    bf16x8 pah = *(const bf16x8*)&Ps0[lo16 * 72 + k2 * 32 + hi4 * 8];
    bf16x8 pal = *(const bf16x8*)&Ps1[lo16 * 72 + k2 * 32 + hi4 * 8];
    #pragma unroll
    for (int n = 0; n < 4; ++n) {
      int vrow = n * 16 + lo16;
      bf16x8 vh = *(const bf16x8*)&Vs0[vrow * 64 + (((k2 * 4 + hi4) ^ (vrow & 7))) * 8];
      bf16x8 vl = *(const bf16x8*)&Vs1[vrow * 64 + (((k2 * 4 + hi4) ^ (vrow & 7))) * 8];
      S.o[n] = MFMA16(pah, vh, S.o[n]);
      S.o[n] = MFMA16(pah, vl, S.o[n]);
      S.o[n] = MFMA16(pal, vh, S.o[n]);
    }
  }
  __builtin_amdgcn_s_setprio(0);
}

__device__ __forceinline__ void qstate_out(QState& S, int q0w, int h,
    u16* out_hi, u16* out_lo, int lo16, int hi4)
{
  #pragma unroll
  for (int n = 0; n < 4; ++n)
    #pragma unroll
    for (int r = 0; r < 4; ++r) {
      float v = S.o[n][r] / S.l_r[r];
      size_t idx = (size_t)(q0w + hi4 * 4 + r) * 1024 + h * 64 + n * 16 + lo16;
      u16 hb = f2bf(v);
      out_hi[idx] = hb;
      out_lo[idx] = f2bf(v - bf2f(hb));
    }
}

// 768 blocks, equal-duration (<=17 tiles each), heavy-first.
__launch_bounds__(256)
__global__ void attn_kernel(const u16* __restrict__ qkv_hi, const u16* __restrict__ qkv_lo,
                            const u16* __restrict__ vT_hi, const u16* __restrict__ vT_lo,
                            u16* __restrict__ out_hi, u16* __restrict__ out_lo,
                            float* __restrict__ part_o, float* __restrict__ part_ml)
{
  int id = blockIdx.x;
  int h, qb, t0, t1, part = 0;
  bool split;
  if (id < 512) {
    qb = 31 - (id >> 5);
    h = (id >> 1) & 15;
    part = id & 1;
    int nh = (qb + 1) >> 1;
    t0 = part ? nh : 0;
    t1 = part ? (qb + 1) : nh;
    split = true;
  } else {
    int rr = id - 512;
    qb = 15 - (rr >> 4);
    h = rr & 15;
    t0 = 0; t1 = qb + 1;
    split = false;
  }
  int kvh = h >> 2, gi = h & 3;
  int tid = threadIdx.x;
  int lane = tid & 63;
  int w = tid >> 6;
  int lo16 = lane & 15, hi4 = lane >> 4;
  int q0w = qb * 64 + w * 16;
  int qoff = kvh * 384 + gi * 64;
  int koff = kvh * 384 + 256;

  __shared__ u16 Ks[2][64 * 64];
  __shared__ u16 Vs[2][64 * 64];
  __shared__ u16 Ps[2][4][16 * 72];
  u16* Ps0 = &Ps[0][w][0];
  u16* Ps1 = &Ps[1][w][0];

  QState S;
  qstate_init(S, qkv_hi, qkv_lo, q0w, qoff, lo16, hi4);

  for (int t = t0; t < t1; ++t) {
    int kv0 = t * 64;
    __syncthreads();
    #pragma unroll
    for (int it = 0; it < 2; ++it) {
      int u = it * 256 + tid;
      int row = u >> 3, ch = u & 7;
      int d = (ch ^ (row & 7)) * 8;
      *(uint4*)&Ks[0][row * 64 + d] = *(const uint4*)(qkv_hi + (size_t)(kv0 + row) * 1536 + koff + ch * 8);
      *(uint4*)&Ks[1][row * 64 + d] = *(const uint4*)(qkv_lo + (size_t)(kv0 + row) * 1536 + koff + ch * 8);
      *(uint4*)&Vs[0][row * 64 + d] = *(const uint4*)(vT_hi + ((size_t)kvh * 64 + row) * 2048 + kv0 + ch * 8);
      *(uint4*)&Vs[1][row * 64 + d] = *(const uint4*)(vT_lo + ((size_t)kvh * 64 + row) * 2048 + kv0 + ch * 8);
    }
    __syncthreads();

    attn_tile(S, kv0, Ks[0], Ks[1], Vs[0], Vs[1], Ps0, Ps1, lo16, hi4);
  }

  if (!split) {
    qstate_out(S, q0w, h, out_hi, out_lo, lo16, hi4);
  } else {
    int pj = ((qb - 16) * 16 + h) * 2 + part;
    float* po  = part_o  + (size_t)pj * 4096;
    float* pml = part_ml + (size_t)pj * 128;
    #pragma unroll
    for (int n = 0; n < 4; ++n)
      #pragma unroll
      for (int r = 0; r < 4; ++r)
        po[(w * 16 + hi4 * 4 + r) * 64 + n * 16 + lo16] = S.o[n][r];
    if (lo16 == 0) {
      #pragma unroll
      for (int r = 0; r < 4; ++r) {
        pml[w * 16 + hi4 * 4 + r] = S.m_r[r];
        pml[64 + w * 16 + hi4 * 4 + r] = S.l_r[r];
      }
    }
  }
}

// merge 2 partials per (h, qb>=16) job
__launch_bounds__(256)
__global__ void attn_combine(const float* __restrict__ part_o, const float* __restrict__ part_ml,
                             u16* __restrict__ out_hi, u16* __restrict__ out_lo)
{
  int job = blockIdx.x;
  int qb = 16 + (job >> 4);
  int h = job & 15;
  const float* po0  = part_o  + (size_t)(job * 2    ) * 4096;
  const float* po1  = part_o  + (size_t)(job * 2 + 1) * 4096;
  const float* pml0 = part_ml + (size_t)(job * 2    ) * 128;
  const float* pml1 = part_ml + (size_t)(job * 2 + 1) * 128;
  int t = threadIdx.x;
  #pragma unroll
  for (int i = 0; i < 16; ++i) {
    int e = i * 256 + t;
    int row = e >> 6, col = e & 63;
    float m0 = pml0[row], m1 = pml1[row];
    float M = fmaxf(m0, m1);
    float e0 = __expf(m0 - M), e1 = __expf(m1 - M);
    float l = pml0[64 + row] * e0 + pml1[64 + row] * e1;
    float v = (po0[row * 64 + col] * e0 + po1[row * 64 + col] * e1) / l;
    size_t idx = (size_t)(qb * 64 + row) * 1024 + h * 64 + col;
    u16 hb = f2bf(v);
    out_hi[idx] = hb;
    out_lo[idx] = f2bf(v - bf2f(hb));
  }
}

// ---------------- Router ----------------
__launch_bounds__(64)
__global__ void router_kernel(const float* __restrict__ x, const float* __restrict__ rw,
                              int* __restrict__ counts, int* __restrict__ esel,
                              int* __restrict__ slotsel, float* __restrict__ wsel)
{
  int t = blockIdx.x;
  int l = threadIdx.x;
  float acc[8] = {0.f, 0.f, 0.f, 0.f, 0.f, 0.f, 0.f, 0.f};
  const float* xr = x + (size_t)t * 1024;
  for (int hh = l; hh < 1024; hh += 64) {
    float xv = xr[hh];
    const float* wp = rw + hh * 8;
    #pragma unroll
    for (int e = 0; e < 8; ++e) acc[e] = fmaf(xv, wp[e], acc[e]);
  }
  #pragma unroll
  for (int e = 0; e < 8; ++e)
    #pragma unroll
    for (int d = 1; d < 64; d <<= 1) acc[e] += __shfl_xor(acc[e], d);
  if (l == 0) {
    int e1 = 0;
    #pragma unroll
    for (int e = 1; e < 8; ++e) if (acc[e] > acc[e1]) e1 = e;
    int e2 = -1;
    #pragma unroll
    for (int e = 0; e < 8; ++e) {
      if (e == e1) continue;
      if (e2 < 0 || acc[e] > acc[e2]) e2 = e;
    }
    float p1 = 1.0f / (1.0f + expf(acc[e2] - acc[e1]));
    float p2 = 1.0f - p1;
    int s1 = atomicAdd(&counts[e1], 1);
    int s2 = atomicAdd(&counts[e2], 1);
    esel[t * 2] = e1; esel[t * 2 + 1] = e2;
    slotsel[t * 2] = s1; slotsel[t * 2 + 1] = s2;
    wsel[t * 2] = p1; wsel[t * 2 + 1] = p2;
  }
}

// ---------------- prefix + pair lists ----------------
__global__ void build_lists_kernel(const int* __restrict__ counts, int* __restrict__ prefix,
                                   const int* __restrict__ esel, const int* __restrict__ slotsel,
                                   int* __restrict__ tok_of_pair, int* __restrict__ pair_idx)
{
  __shared__ int pfx[8];
  if (threadIdx.x == 0) {
    int a = 0;
    for (int e = 0; e < 8; ++e) { pfx[e] = a; prefix[e] = a; a += counts[e]; }
  }
  __syncthreads();
  for (int t = threadIdx.x; t < 2048; t += 256) {
    #pragma unroll
    for (int k = 0; k < 2; ++k) {
      int e = esel[t * 2 + k];
      int row = pfx[e] + slotsel[t * 2 + k];
      tok_of_pair[row] = t;
      pair_idx[t * 2 + k] = row;
    }
  }
}

// ---------------- final combine: out = hattn + sum over pairs/splits (bf16 partials) ----
__launch_bounds__(256)
__global__ void final_kernel(const float* __restrict__ hattn, const u16* __restrict__ y,
                             const int* __restrict__ pair_idx, const float* __restrict__ wsel,
                             float* __restrict__ out)
{
  int t = blockIdx.x;
  int c = threadIdx.x * 4;
  int p0 = pair_idx[t * 2], p1 = pair_idx[t * 2 + 1];
  float w0 = wsel[t * 2], w1 = wsel[t * 2 + 1];
  float4 a = *(const float4*)(hattn + (size_t)t * 1024 + c);
  float y0[4] = {0.f, 0.f, 0.f, 0.f};
  float y1[4] = {0.f, 0.f, 0.f, 0.f};
  #pragma unroll
  for (int s = 0; s < 4; ++s) {
    const u16* base = y + (size_t)s * 4096 * 1024;
    uint2 v0 = *(const uint2*)(base + (size_t)p0 * 1024 + c);
    uint2 v1 = *(const uint2*)(base + (size_t)p1 * 1024 + c);
    y0[0] += bf2f((u16)(v0.x & 0xffff)); y0[1] += bf2f((u16)(v0.x >> 16));
    y0[2] += bf2f((u16)(v0.y & 0xffff)); y0[3] += bf2f((u16)(v0.y >> 16));
    y1[0] += bf2f((u16)(v1.x & 0xffff)); y1[1] += bf2f((u16)(v1.x >> 16));
    y1[2] += bf2f((u16)(v1.y & 0xffff)); y1[3] += bf2f((u16)(v1.y >> 16));
  }
  float4 r;
  r.x = a.x + w0 * y0[0] + w1 * y1[0];
  r.y = a.y + w0 * y0[1] + w1 * y1[1];
  r.z = a.z + w0 * y0[2] + w1 * y1[2];
  r.w = a.w + w0 * y0[3] + w1 * y1[3];
  *(float4*)(out + (size_t)t * 1024 + c) = r;
}

extern "C" void kernel_launch(void* const* d_in, const int* in_sizes, int n_in,
                              void* d_out, int out_size, void* d_ws, size_t ws_size,
                              hipStream_t stream)
{
  const float* hidden   = (const float*)d_in[0];
  const float* ln1_w    = (const float*)d_in[1];
  const float* ln1_b    = (const float*)d_in[2];
  const float* ln2_w    = (const float*)d_in[3];
  const float* ln2_b    = (const float*)d_in[4];
  const float* qkv_w    = (const float*)d_in[5];
  const float* proj_w   = (const float*)d_in[6];
  const float* router_w = (const float*)d_in[7];
  const float* moe_w1   = (const float*)d_in[8];
  const float* moe_w2   = (const float*)d_in[9];
  float* out = (float*)d_out;

  char* ws = (char*)d_ws;
  size_t off = 0;
  auto alloc = [&](size_t bytes) -> void* {
    void* p = (void*)(ws + off);
    off += (bytes + 255) & ~(size_t)255;
    return p;
  };

  // ---- long-lived buffers ----
  u16* wT      = (u16*)alloc(8ull * 4096 * 1024 * 2);   // w1t then w2t (64 MB)
  float* hattn = (float*)alloc(2048ull * 1024 * 4);     // 8 MB
  u16* x_hi    = (u16*)alloc(2048ull * 1024 * 2);       // 4 MB
  u16* act     = (u16*)alloc(4096ull * 4096 * 2);       // 32 MB
  u16* ybuf    = (u16*)alloc(4ull * 4096 * 1024 * 4);   // 32 MB used; 64 MB reserved (overlay)

  // ---- short-lived buffers overlaid INSIDE ybuf (dead before fc2 writes it) ----
  char* ov = (char*)ybuf;
  size_t oo = 0;
  auto oalloc = [&](size_t bytes) -> void* {
    void* p = (void*)(ov + oo);
    oo += (bytes + 255) & ~(size_t)255;
    return p;
  };
  u16* ln1_hi  = (u16*)oalloc(2048ull * 1024 * 2);
  u16* ln1_lo  = (u16*)oalloc(2048ull * 1024 * 2);
  u16* qw_hi   = (u16*)oalloc(1536ull * 1024 * 2);
  u16* qw_lo   = (u16*)oalloc(1536ull * 1024 * 2);
  u16* pw_hi   = (u16*)oalloc(1024ull * 1024 * 2);
  u16* pw_lo   = (u16*)oalloc(1024ull * 1024 * 2);
  u16* qkv_hi  = (u16*)oalloc(2048ull * 1536 * 2);
  u16* qkv_lo  = (u16*)oalloc(2048ull * 1536 * 2);
  u16* vt_hi   = (u16*)oalloc(4ull * 64 * 2048 * 2);
  u16* vt_lo   = (u16*)oalloc(4ull * 64 * 2048 * 2);
  u16* at_hi   = (u16*)oalloc(2048ull * 1024 * 2);
  u16* at_lo   = (u16*)oalloc(2048ull * 1024 * 2);
  float* x_f32 = (float*)oalloc(2048ull * 1024 * 4);
  float* part_o  = (float*)oalloc(512ull * 4096 * 4);
  float* part_ml = (float*)oalloc(512ull * 128 * 4);

  // ---- small control buffers ----
  int* counts  = (int*)alloc(8 * 4);
  int* prefix  = (int*)alloc(8 * 4);
  int* esel    = (int*)alloc(2048ull * 2 * 4);
  int* slotsel = (int*)alloc(2048ull * 2 * 4);
  int* topair  = (int*)alloc(4096ull * 4);
  int* pairidx = (int*)alloc(2048ull * 2 * 4);
  float* wsel  = (float*)alloc(2048ull * 2 * 4);

  hipMemsetAsync(counts, 0, 8 * 4, stream);

  ln_kernel<true, false><<<2048, 256, 0, stream>>>(hidden, ln1_w, ln1_b, ln1_hi, ln1_lo, nullptr);

  convert_split_kernel<<<1536, 256, 0, stream>>>(qkv_w, qw_hi, qw_lo, 1536 * 1024 / 4);
  convert_split_kernel<<<1024, 256, 0, stream>>>(proj_w, pw_hi, pw_lo, 1024 * 1024 / 4);

  gemm_kernel<0><<<dim3(12, 16, 1), 256, 0, stream>>>(
      ln1_hi, ln1_lo, qw_hi, qw_lo, 1536, 1024,
      qkv_hi, qkv_lo, nullptr, nullptr, nullptr, nullptr, nullptr);

  vtrans_kernel<<<dim3(64, 2, 4), dim3(32, 8), 0, stream>>>(qkv_hi, vt_hi);
  vtrans_kernel<<<dim3(64, 2, 4), dim3(32, 8), 0, stream>>>(qkv_lo, vt_lo);

  attn_kernel<<<768, 256, 0, stream>>>(qkv_hi, qkv_lo, vt_hi, vt_lo, at_hi, at_lo, part_o, part_ml);
  attn_combine<<<256, 256, 0, stream>>>(part_o, part_ml, at_hi, at_lo);

  gemm_kernel<1><<<dim3(8, 16, 1), 256, 0, stream>>>(
      at_hi, at_lo, pw_hi, pw_lo, 1024, 1024,
      nullptr, nullptr, hattn, hidden, nullptr, nullptr, nullptr);

  ln_kernel<false, true><<<2048, 256, 0, stream>>>(hattn, ln2_w, ln2_b, x_hi, nullptr, x_f32);

  router_kernel<<<2048, 64, 0, stream>>>(x_f32, router_w, counts, esel, slotsel, wsel);
  build_lists_kernel<<<1, 256, 0, stream>>>(counts, prefix, esel, slotsel, topair, pairidx);

  transpose_convert_kernel<<<dim3(64, 16, 8), 256, 0, stream>>>(moe_w1, wT, 1024, 4096);

  // fc1: 128x256 tile, grid (16,16,8), XCD = L%8 = e
  fc1_kernel<<<dim3(16, 16, 8), 256, 0, stream>>>(x_hi, wT, act, topair, counts, prefix);

  transpose_convert_kernel<<<dim3(16, 64, 8), 256, 0, stream>>>(moe_w2, wT, 4096, 1024);

  gemm_kernel<3><<<dim3(32, 16, 8), 256, 0, stream>>>(
      act, nullptr, wT, nullptr, 1024, 4096,
      ybuf, nullptr, nullptr, nullptr, topair, counts, prefix);

  final_kernel<<<2048, 256, 0, stream>>>(hattn, ybuf, pairidx, wsel, out);
}

// Round 17
// 456.071 us; speedup vs baseline: 1.0621x; 1.0621x over previous
//
#include <hip/hip_runtime.h>
#include <cstdint>
#include <cstddef>

typedef unsigned short u16;
typedef __attribute__((ext_vector_type(8))) short bf16x8;
typedef __attribute__((ext_vector_type(4))) float f32x4;

#define MFMA16(a, b, c) __builtin_amdgcn_mfma_f32_16x16x32_bf16((a), (b), (c), 0, 0, 0)

__device__ __forceinline__ u16 f2bf(float f) {
  uint32_t u = __builtin_bit_cast(uint32_t, f);
  u += 0x7fffu + ((u >> 16) & 1u);
  return (u16)(u >> 16);
}
__device__ __forceinline__ float bf2f(u16 h) {
  uint32_t u = ((uint32_t)h) << 16;
  return __builtin_bit_cast(float, u);
}

__device__ __forceinline__ void gload_lds16(const void* g, void* l) {
  __builtin_amdgcn_global_load_lds(
      (const __attribute__((address_space(1))) uint32_t*)g,
      (__attribute__((address_space(3))) uint32_t*)l, 16, 0, 0);
}

// ---------------- LayerNorm (writes bf16 hi [, lo] [, f32]) ----------------
template<bool WRITE_LO, bool WRITE_F32>
__launch_bounds__(256)
__global__ void ln_kernel(const float* __restrict__ in,
                          const float* __restrict__ w, const float* __restrict__ b,
                          u16* __restrict__ out_hi, u16* __restrict__ out_lo,
                          float* __restrict__ out_f32)
{
  int row = blockIdx.x;
  int tid = threadIdx.x;
  const float* x = in + (size_t)row * 1024;
  float4 v = *(const float4*)(x + tid * 4);
  float s  = v.x + v.y + v.z + v.w;
  float s2 = v.x*v.x + v.y*v.y + v.z*v.z + v.w*v.w;
  #pragma unroll
  for (int d = 1; d < 64; d <<= 1) { s += __shfl_xor(s, d); s2 += __shfl_xor(s2, d); }
  __shared__ float red[2][4];
  int wid = tid >> 6;
  if ((tid & 63) == 0) { red[0][wid] = s; red[1][wid] = s2; }
  __syncthreads();
  s  = red[0][0] + red[0][1] + red[0][2] + red[0][3];
  s2 = red[1][0] + red[1][1] + red[1][2] + red[1][3];
  float mean = s * (1.0f / 1024.0f);
  float var  = s2 * (1.0f / 1024.0f) - mean * mean;
  float rstd = rsqrtf(var + 1e-5f);
  float vv[4] = {v.x, v.y, v.z, v.w};
  #pragma unroll
  for (int j = 0; j < 4; ++j) {
    int c = tid * 4 + j;
    float y = (vv[j] - mean) * rstd * w[c] + b[c];
    size_t idx = (size_t)row * 1024 + c;
    u16 hb = f2bf(y);
    out_hi[idx] = hb;
    if (WRITE_LO)  out_lo[idx] = f2bf(y - bf2f(hb));
    if (WRITE_F32) out_f32[idx] = y;
  }
}

// ---------------- f32 -> bf16 hi/lo split (flat) ----------------
__global__ void convert_split_kernel(const float* __restrict__ in,
                                     u16* __restrict__ hi, u16* __restrict__ lo, int n4)
{
  int i = blockIdx.x * blockDim.x + threadIdx.x;
  if (i >= n4) return;
  float4 v = *(const float4*)(in + (size_t)i * 4);
  float a[4] = {v.x, v.y, v.z, v.w};
  u16 hh[4], ll[4];
  #pragma unroll
  for (int j = 0; j < 4; ++j) {
    hh[j] = f2bf(a[j]);
    ll[j] = f2bf(a[j] - bf2f(hh[j]));
  }
  uint2 hp, lp;
  hp.x = (uint32_t)hh[0] | ((uint32_t)hh[1] << 16);
  hp.y = (uint32_t)hh[2] | ((uint32_t)hh[3] << 16);
  lp.x = (uint32_t)ll[0] | ((uint32_t)ll[1] << 16);
  lp.y = (uint32_t)ll[2] | ((uint32_t)ll[3] << 16);
  *(uint2*)(hi + (size_t)i * 4) = hp;
  *(uint2*)(lo + (size_t)i * 4) = lp;
}

// ---------------- transpose + convert f32(R,C) -> bf16(C,R), per expert ----------------
__launch_bounds__(256)
__global__ void transpose_convert_kernel(const float* __restrict__ in, u16* __restrict__ out,
                                         int R, int C)
{
  __shared__ float t[64][65];
  size_t ebase = (size_t)blockIdx.z * R * C;
  int c0 = blockIdx.x * 64, r0 = blockIdx.y * 64;
  int tid = threadIdx.x;
  #pragma unroll
  for (int q = 0; q < 4; ++q) {
    int u = q * 256 + tid;
    int row = u >> 4, col4 = u & 15;
    float4 v = *(const float4*)(in + ebase + (size_t)(r0 + row) * C + c0 + col4 * 4);
    t[row][col4 * 4 + 0] = v.x;
    t[row][col4 * 4 + 1] = v.y;
    t[row][col4 * 4 + 2] = v.z;
    t[row][col4 * 4 + 3] = v.w;
  }
  __syncthreads();
  #pragma unroll
  for (int q = 0; q < 2; ++q) {
    int u = q * 256 + tid;
    int orow = u >> 3, oseg = u & 7;
    u16 tmp[8];
    #pragma unroll
    for (int j = 0; j < 8; ++j)
      tmp[j] = f2bf(t[oseg * 8 + j][orow]);
    *(uint4*)(out + ebase + (size_t)(c0 + orow) * R + r0 + oseg * 8) = *(uint4*)tmp;
  }
}

// ---------------- V transpose within qkv: vT[kvh][d][s] ----------------
__global__ void vtrans_kernel(const u16* __restrict__ qkv, u16* __restrict__ vT)
{
  __shared__ u16 t[32][34];
  int kvh = blockIdx.z;
  int s0 = blockIdx.x * 32, d0 = blockIdx.y * 32;
  int tx = threadIdx.x, ty = threadIdx.y;
  #pragma unroll
  for (int i = 0; i < 4; ++i)
    t[ty + 8*i][tx] = qkv[(size_t)(s0 + ty + 8*i) * 1536 + kvh * 384 + 320 + d0 + tx];
  __syncthreads();
  #pragma unroll
  for (int i = 0; i < 4; ++i)
    vT[((size_t)kvh * 64 + d0 + ty + 8*i) * 2048 + (s0 + tx)] = t[tx][ty + 8*i];
}

// ---------------- GEMM: C[M,N] = A[M,K] * B[N,K]^T  (bf16 MFMA, 2-buf dbuf) --------
// MODE 0: qkv (split in, bf16 hi/lo out)    MODE 1: proj+resid (split in, f32 out)
// MODE 2: fc1 gathered+gelu, XCD-remap e=xcd
// MODE 3: fc2 split-K x4 -> bf16 partials, XCD-remap co-locates A/B sharers
// T2 swizzle (rule #21): LDS dest linear; global source chunk p -> p ^ ((row>>1)&3)
// within each 64B row; fragment reads use chunk = hi4 ^ ((lo16>>1)&3).
template<int MODE>
__launch_bounds__(256, (MODE < 2) ? 2 : 4)
__global__ void gemm_kernel(const u16* __restrict__ Ahi, const u16* __restrict__ Alo,
                            const u16* __restrict__ Bhi, const u16* __restrict__ Blo,
                            int N, int K,
                            u16* __restrict__ Cb_hi, u16* __restrict__ Cb_lo,
                            float* __restrict__ Cf, const float* __restrict__ resid,
                            const int* __restrict__ tok_of_pair,
                            const int* __restrict__ counts, const int* __restrict__ prefix)
{
  constexpr bool SPLIT = (MODE < 2);
  int bn = blockIdx.x, bm = blockIdx.y;
  int row_base = 0;
  int count = 1 << 30;
  int kbeg = 0, kend = K;
  if constexpr (MODE >= 2) {
    int L = blockIdx.x + 32 * (blockIdx.y + 16 * blockIdx.z);
    int xcd = L & 7, idx = L >> 3;
    int e;
    if constexpr (MODE == 2) {
      bn = idx & 31;
      e  = xcd;
      bm = (idx >> 5) & 15;
    } else {
      bn = idx & 7;
      int G = xcd * 64 + (idx >> 3);
      int s = G >> 7;
      int rem = G & 127;
      e  = rem >> 4;
      bm = rem & 15;
      int kc = K >> 2;
      kbeg = s * kc; kend = kbeg + kc;
      Cb_hi += (size_t)s * 4096 * 1024;
    }
    count = counts[e];
    if (bm * 128 >= count) return;
    row_base = prefix[e];
    Bhi += (size_t)e * N * K;
  }
  __shared__ u16 As[2][SPLIT ? 2 : 1][128 * 32];
  __shared__ u16 Bs[2][SPLIT ? 2 : 1][128 * 32];

  int tid = threadIdx.x;
  int lane = tid & 63;
  int lo16 = lane & 15, hi4 = lane >> 4;
  int wid = tid >> 6, wr = wid >> 1, wc = wid & 1;

  const u16* gA[2][2];
  const u16* gB[2][2];
  int eidx[2];
  #pragma unroll
  for (int q = 0; q < 2; ++q) {
    int el = (q * 256 + tid) * 8;
    int r = el >> 5;
    int kc = ((((el >> 3) & 3) ^ ((r >> 1) & 3)) * 8);
    eidx[q] = el;
    if constexpr (MODE == 2) {
      int lim = count - bm * 128 - 1;
      int lr = r < lim ? r : lim;
      int token = tok_of_pair[row_base + bm * 128 + lr];
      gA[q][0] = Ahi + (size_t)token * K + kc;
    } else if constexpr (MODE == 3) {
      int lim = count - bm * 128 - 1;
      int lr = r < lim ? r : lim;
      gA[q][0] = Ahi + (size_t)(row_base + bm * 128 + lr) * K + kc;
    } else {
      gA[q][0] = Ahi + (size_t)(bm * 128 + r) * K + kc;
      gA[q][1] = Alo + (size_t)(bm * 128 + r) * K + kc;
    }
    gB[q][0] = Bhi + (size_t)(bn * 128 + r) * K + kc;
    if constexpr (SPLIT) gB[q][1] = Blo + (size_t)(bn * 128 + r) * K + kc;
  }

  auto stage = [&](int buf, int k0) {
    #pragma unroll
    for (int q = 0; q < 2; ++q) {
      gload_lds16(gA[q][0] + k0, &As[buf][0][eidx[q]]);
      gload_lds16(gB[q][0] + k0, &Bs[buf][0][eidx[q]]);
      if constexpr (SPLIT) {
        gload_lds16(gA[q][1] + k0, &As[buf][1][eidx[q]]);
        gload_lds16(gB[q][1] + k0, &Bs[buf][1][eidx[q]]);
      }
    }
  };

  const f32x4 zf = {0.f, 0.f, 0.f, 0.f};
  f32x4 acc[4][4];
  #pragma unroll
  for (int m = 0; m < 4; ++m)
    #pragma unroll
    for (int n = 0; n < 4; ++n) acc[m][n] = zf;

  stage(0, kbeg);
  __syncthreads();

  int csw = ((hi4 ^ ((lo16 >> 1) & 3)) * 8);

  int cur = 0;
  for (int k0 = kbeg; k0 < kend; k0 += 32, cur ^= 1) {
    if (k0 + 32 < kend) stage(cur ^ 1, k0 + 32);

    bf16x8 a0[4], b0[4], a1[4], b1[4];
    #pragma unroll
    for (int m = 0; m < 4; ++m)
      a0[m] = *(const bf16x8*)&As[cur][0][(wr * 64 + m * 16 + lo16) * 32 + csw];
    #pragma unroll
    for (int n = 0; n < 4; ++n)
      b0[n] = *(const bf16x8*)&Bs[cur][0][(wc * 64 + n * 16 + lo16) * 32 + csw];
    if constexpr (SPLIT) {
      #pragma unroll
      for (int m = 0; m < 4; ++m)
        a1[m] = *(const bf16x8*)&As[cur][1][(wr * 64 + m * 16 + lo16) * 32 + csw];
      #pragma unroll
      for (int n = 0; n < 4; ++n)
        b1[n] = *(const bf16x8*)&Bs[cur][1][(wc * 64 + n * 16 + lo16) * 32 + csw];
    }
    #pragma unroll
    for (int m = 0; m < 4; ++m)
      #pragma unroll
      for (int n = 0; n < 4; ++n) {
        acc[m][n] = MFMA16(a0[m], b0[n], acc[m][n]);
        if constexpr (SPLIT) {
          acc[m][n] = MFMA16(a0[m], b1[n], acc[m][n]);
          acc[m][n] = MFMA16(a1[m], b0[n], acc[m][n]);
        }
      }
    __syncthreads();
  }

  #pragma unroll
  for (int m = 0; m < 4; ++m)
    #pragma unroll
    for (int n = 0; n < 4; ++n)
      #pragma unroll
      for (int r = 0; r < 4; ++r) {
        int lr = wr * 64 + m * 16 + hi4 * 4 + r;
        int col = bn * 128 + wc * 64 + n * 16 + lo16;
        float v = acc[m][n][r];
        if constexpr (MODE == 0) {
          size_t idx = (size_t)(bm * 128 + lr) * N + col;
          u16 hb = f2bf(v);
          Cb_hi[idx] = hb;
          Cb_lo[idx] = f2bf(v - bf2f(hb));
        } else if constexpr (MODE == 1) {
          size_t idx = (size_t)(bm * 128 + lr) * N + col;
          Cf[idx] = v + resid[idx];
        } else if constexpr (MODE == 2) {
          if (bm * 128 + lr < count) {
            size_t idx = (size_t)(row_base + bm * 128 + lr) * N + col;
            float g = 0.5f * v * (1.0f + erff(v * 0.70710678118654752f));
            Cb_hi[idx] = f2bf(g);
          }
        } else {
          if (bm * 128 + lr < count) {
            size_t idx = (size_t)(row_base + bm * 128 + lr) * N + col;
            Cb_hi[idx] = f2bf(v);
          }
        }
      }
}

// ---------------- Flash attention, causal GQA, split-bf16, split-KV balance ----------
struct QState {
  bf16x8 qf[2][2];
  f32x4 o[4];
  float m_r[4], l_r[4];
  int qrow[4];
};

__device__ __forceinline__ void qstate_init(QState& S,
    const u16* qkv_hi, const u16* qkv_lo, int q0w, int qoff, int lo16, int hi4)
{
  const u16* ph = qkv_hi + (size_t)(q0w + lo16) * 1536 + qoff + hi4 * 8;
  const u16* pl = qkv_lo + (size_t)(q0w + lo16) * 1536 + qoff + hi4 * 8;
  S.qf[0][0] = *(const bf16x8*)ph;  S.qf[0][1] = *(const bf16x8*)(ph + 32);
  S.qf[1][0] = *(const bf16x8*)pl;  S.qf[1][1] = *(const bf16x8*)(pl + 32);
  const f32x4 zf = {0.f, 0.f, 0.f, 0.f};
  #pragma unroll
  for (int r = 0; r < 4; ++r) { S.m_r[r] = -INFINITY; S.l_r[r] = 0.f; S.qrow[r] = q0w + hi4 * 4 + r; }
  #pragma unroll
  for (int n = 0; n < 4; ++n) S.o[n] = zf;
}

__device__ __forceinline__ void attn_tile(QState& S, int kv0,
    const u16* Ks0, const u16* Ks1, const u16* Vs0, const u16* Vs1,
    u16* Ps0, u16* Ps1, int lo16, int hi4)
{
  const f32x4 zf = {0.f, 0.f, 0.f, 0.f};
  f32x4 sc[4];
  __builtin_amdgcn_s_setprio(1);
  #pragma unroll
  for (int c2 = 0; c2 < 4; ++c2) {
    sc[c2] = zf;
    int krow = c2 * 16 + lo16;
    const u16* kb  = &Ks0[krow * 64];
    const u16* kbl = &Ks1[krow * 64];
    bf16x8 kh0 = *(const bf16x8*)&kb [((hi4    ) ^ (krow & 7)) * 8];
    bf16x8 kh1 = *(const bf16x8*)&kb [((hi4 + 4) ^ (krow & 7)) * 8];
    bf16x8 kl0 = *(const bf16x8*)&kbl[((hi4    ) ^ (krow & 7)) * 8];
    bf16x8 kl1 = *(const bf16x8*)&kbl[((hi4 + 4) ^ (krow & 7)) * 8];
    sc[c2] = MFMA16(S.qf[0][0], kh0, sc[c2]);
    sc[c2] = MFMA16(S.qf[0][1], kh1, sc[c2]);
    sc[c2] = MFMA16(S.qf[0][0], kl0, sc[c2]);
    sc[c2] = MFMA16(S.qf[0][1], kl1, sc[c2]);
    sc[c2] = MFMA16(S.qf[1][0], kh0, sc[c2]);
    sc[c2] = MFMA16(S.qf[1][1], kh1, sc[c2]);
  }
  __builtin_amdgcn_s_setprio(0);

  float tmax[4] = {-INFINITY, -INFINITY, -INFINITY, -INFINITY};
  #pragma unroll
  for (int c2 = 0; c2 < 4; ++c2) {
    int kv = kv0 + c2 * 16 + lo16;
    #pragma unroll
    for (int r = 0; r < 4; ++r) {
      float sv = sc[c2][r] * 0.125f;
      if (kv > S.qrow[r]) sv = -1e30f;
      sc[c2][r] = sv;
      tmax[r] = fmaxf(tmax[r], sv);
    }
  }
  #pragma unroll
  for (int d = 1; d < 16; d <<= 1)
    #pragma unroll
    for (int r = 0; r < 4; ++r)
      tmax[r] = fmaxf(tmax[r], __shfl_xor(tmax[r], d));
  float rs[4], rowsum[4];
  #pragma unroll
  for (int r = 0; r < 4; ++r) {
    float mn = fmaxf(S.m_r[r], tmax[r]);
    rs[r] = __expf(S.m_r[r] - mn);
    S.m_r[r] = mn;
    rowsum[r] = 0.f;
  }
  #pragma unroll
  for (int c2 = 0; c2 < 4; ++c2)
    #pragma unroll
    for (int r = 0; r < 4; ++r) {
      float pv = __expf(sc[c2][r] - S.m_r[r]);
      sc[c2][r] = pv;
      rowsum[r] += pv;
    }
  #pragma unroll
  for (int d = 1; d < 16; d <<= 1)
    #pragma unroll
    for (int r = 0; r < 4; ++r)
      rowsum[r] += __shfl_xor(rowsum[r], d);
  #pragma unroll
  for (int r = 0; r < 4; ++r) S.l_r[r] = S.l_r[r] * rs[r] + rowsum[r];
  #pragma unroll
  for (int n = 0; n < 4; ++n)
    #pragma unroll
    for (int r = 0; r < 4; ++r) S.o[n][r] *= rs[r];

  #pragma unroll
  for (int c2 = 0; c2 < 4; ++c2)
    #pragma unroll
    for (int r = 0; r < 4; ++r) {
      float pv = sc[c2][r];
      u16 ph = f2bf(pv);
      int pidx = (hi4 * 4 + r) * 72 + c2 * 16 + lo16;
      Ps0[pidx] = ph;
      Ps1[pidx] = f2bf(pv - bf2f(ph));
    }

  __builtin_amdgcn_s_setprio(1);
  #pragma unroll
  for (int k2 = 0; k2 < 2; ++k2) {
    bf16x8 pah = *(const bf16x8*)&Ps0[lo16 * 72 + k2 * 32 + hi4 * 8];
    bf16x8 pal = *(const bf16x8*)&Ps1[lo16 * 72 + k2 * 32 + hi4 * 8];
    #pragma unroll
    for (int n = 0; n < 4; ++n) {
      int vrow = n * 16 + lo16;
      bf16x8 vh = *(const bf16x8*)&Vs0[vrow * 64 + (((k2 * 4 + hi4) ^ (vrow & 7))) * 8];
      bf16x8 vl = *(const bf16x8*)&Vs1[vrow * 64 + (((k2 * 4 + hi4) ^ (vrow & 7))) * 8];
      S.o[n] = MFMA16(pah, vh, S.o[n]);
      S.o[n] = MFMA16(pah, vl, S.o[n]);
      S.o[n] = MFMA16(pal, vh, S.o[n]);
    }
  }
  __builtin_amdgcn_s_setprio(0);
}

__device__ __forceinline__ void qstate_out(QState& S, int q0w, int h,
    u16* out_hi, u16* out_lo, int lo16, int hi4)
{
  #pragma unroll
  for (int n = 0; n < 4; ++n)
    #pragma unroll
    for (int r = 0; r < 4; ++r) {
      float v = S.o[n][r] / S.l_r[r];
      size_t idx = (size_t)(q0w + hi4 * 4 + r) * 1024 + h * 64 + n * 16 + lo16;
      u16 hb = f2bf(v);
      out_hi[idx] = hb;
      out_lo[idx] = f2bf(v - bf2f(hb));
    }
}

// 768 blocks, equal-duration (<=17 tiles each), heavy-first.
__launch_bounds__(256)
__global__ void attn_kernel(const u16* __restrict__ qkv_hi, const u16* __restrict__ qkv_lo,
                            const u16* __restrict__ vT_hi, const u16* __restrict__ vT_lo,
                            u16* __restrict__ out_hi, u16* __restrict__ out_lo,
                            float* __restrict__ part_o, float* __restrict__ part_ml)
{
  int id = blockIdx.x;
  int h, qb, t0, t1, part = 0;
  bool split;
  if (id < 512) {
    qb = 31 - (id >> 5);
    h = (id >> 1) & 15;
    part = id & 1;
    int nh = (qb + 1) >> 1;
    t0 = part ? nh : 0;
    t1 = part ? (qb + 1) : nh;
    split = true;
  } else {
    int rr = id - 512;
    qb = 15 - (rr >> 4);
    h = rr & 15;
    t0 = 0; t1 = qb + 1;
    split = false;
  }
  int kvh = h >> 2, gi = h & 3;
  int tid = threadIdx.x;
  int lane = tid & 63;
  int w = tid >> 6;
  int lo16 = lane & 15, hi4 = lane >> 4;
  int q0w = qb * 64 + w * 16;
  int qoff = kvh * 384 + gi * 64;
  int koff = kvh * 384 + 256;

  __shared__ u16 Ks[2][64 * 64];
  __shared__ u16 Vs[2][64 * 64];
  __shared__ u16 Ps[2][4][16 * 72];
  u16* Ps0 = &Ps[0][w][0];
  u16* Ps1 = &Ps[1][w][0];

  QState S;
  qstate_init(S, qkv_hi, qkv_lo, q0w, qoff, lo16, hi4);

  for (int t = t0; t < t1; ++t) {
    int kv0 = t * 64;
    __syncthreads();
    #pragma unroll
    for (int it = 0; it < 2; ++it) {
      int u = it * 256 + tid;
      int row = u >> 3, ch = u & 7;
      int d = (ch ^ (row & 7)) * 8;
      *(uint4*)&Ks[0][row * 64 + d] = *(const uint4*)(qkv_hi + (size_t)(kv0 + row) * 1536 + koff + ch * 8);
      *(uint4*)&Ks[1][row * 64 + d] = *(const uint4*)(qkv_lo + (size_t)(kv0 + row) * 1536 + koff + ch * 8);
      *(uint4*)&Vs[0][row * 64 + d] = *(const uint4*)(vT_hi + ((size_t)kvh * 64 + row) * 2048 + kv0 + ch * 8);
      *(uint4*)&Vs[1][row * 64 + d] = *(const uint4*)(vT_lo + ((size_t)kvh * 64 + row) * 2048 + kv0 + ch * 8);
    }
    __syncthreads();

    attn_tile(S, kv0, Ks[0], Ks[1], Vs[0], Vs[1], Ps0, Ps1, lo16, hi4);
  }

  if (!split) {
    qstate_out(S, q0w, h, out_hi, out_lo, lo16, hi4);
  } else {
    int pj = ((qb - 16) * 16 + h) * 2 + part;
    float* po  = part_o  + (size_t)pj * 4096;
    float* pml = part_ml + (size_t)pj * 128;
    #pragma unroll
    for (int n = 0; n < 4; ++n)
      #pragma unroll
      for (int r = 0; r < 4; ++r)
        po[(w * 16 + hi4 * 4 + r) * 64 + n * 16 + lo16] = S.o[n][r];
    if (lo16 == 0) {
      #pragma unroll
      for (int r = 0; r < 4; ++r) {
        pml[w * 16 + hi4 * 4 + r] = S.m_r[r];
        pml[64 + w * 16 + hi4 * 4 + r] = S.l_r[r];
      }
    }
  }
}

// merge 2 partials per (h, qb>=16) job
__launch_bounds__(256)
__global__ void attn_combine(const float* __restrict__ part_o, const float* __restrict__ part_ml,
                             u16* __restrict__ out_hi, u16* __restrict__ out_lo)
{
  int job = blockIdx.x;
  int qb = 16 + (job >> 4);
  int h = job & 15;
  const float* po0  = part_o  + (size_t)(job * 2    ) * 4096;
  const float* po1  = part_o  + (size_t)(job * 2 + 1) * 4096;
  const float* pml0 = part_ml + (size_t)(job * 2    ) * 128;
  const float* pml1 = part_ml + (size_t)(job * 2 + 1) * 128;
  int t = threadIdx.x;
  #pragma unroll
  for (int i = 0; i < 16; ++i) {
    int e = i * 256 + t;
    int row = e >> 6, col = e & 63;
    float m0 = pml0[row], m1 = pml1[row];
    float M = fmaxf(m0, m1);
    float e0 = __expf(m0 - M), e1 = __expf(m1 - M);
    float l = pml0[64 + row] * e0 + pml1[64 + row] * e1;
    float v = (po0[row * 64 + col] * e0 + po1[row * 64 + col] * e1) / l;
    size_t idx = (size_t)(qb * 64 + row) * 1024 + h * 64 + col;
    u16 hb = f2bf(v);
    out_hi[idx] = hb;
    out_lo[idx] = f2bf(v - bf2f(hb));
  }
}

// ---------------- Router ----------------
__launch_bounds__(64)
__global__ void router_kernel(const float* __restrict__ x, const float* __restrict__ rw,
                              int* __restrict__ counts, int* __restrict__ esel,
                              int* __restrict__ slotsel, float* __restrict__ wsel)
{
  int t = blockIdx.x;
  int l = threadIdx.x;
  float acc[8] = {0.f, 0.f, 0.f, 0.f, 0.f, 0.f, 0.f, 0.f};
  const float* xr = x + (size_t)t * 1024;
  for (int hh = l; hh < 1024; hh += 64) {
    float xv = xr[hh];
    const float* wp = rw + hh * 8;
    #pragma unroll
    for (int e = 0; e < 8; ++e) acc[e] = fmaf(xv, wp[e], acc[e]);
  }
  #pragma unroll
  for (int e = 0; e < 8; ++e)
    #pragma unroll
    for (int d = 1; d < 64; d <<= 1) acc[e] += __shfl_xor(acc[e], d);
  if (l == 0) {
    int e1 = 0;
    #pragma unroll
    for (int e = 1; e < 8; ++e) if (acc[e] > acc[e1]) e1 = e;
    int e2 = -1;
    #pragma unroll
    for (int e = 0; e < 8; ++e) {
      if (e == e1) continue;
      if (e2 < 0 || acc[e] > acc[e2]) e2 = e;
    }
    float p1 = 1.0f / (1.0f + expf(acc[e2] - acc[e1]));
    float p2 = 1.0f - p1;
    int s1 = atomicAdd(&counts[e1], 1);
    int s2 = atomicAdd(&counts[e2], 1);
    esel[t * 2] = e1; esel[t * 2 + 1] = e2;
    slotsel[t * 2] = s1; slotsel[t * 2 + 1] = s2;
    wsel[t * 2] = p1; wsel[t * 2 + 1] = p2;
  }
}

// ---------------- prefix + pair lists ----------------
__global__ void build_lists_kernel(const int* __restrict__ counts, int* __restrict__ prefix,
                                   const int* __restrict__ esel, const int* __restrict__ slotsel,
                                   int* __restrict__ tok_of_pair, int* __restrict__ pair_idx)
{
  __shared__ int pfx[8];
  if (threadIdx.x == 0) {
    int a = 0;
    for (int e = 0; e < 8; ++e) { pfx[e] = a; prefix[e] = a; a += counts[e]; }
  }
  __syncthreads();
  for (int t = threadIdx.x; t < 2048; t += 256) {
    #pragma unroll
    for (int k = 0; k < 2; ++k) {
      int e = esel[t * 2 + k];
      int row = pfx[e] + slotsel[t * 2 + k];
      tok_of_pair[row] = t;
      pair_idx[t * 2 + k] = row;
    }
  }
}

// ---------------- final combine: out = hattn + sum over pairs/splits (bf16 partials) ----
__launch_bounds__(256)
__global__ void final_kernel(const float* __restrict__ hattn, const u16* __restrict__ y,
                             const int* __restrict__ pair_idx, const float* __restrict__ wsel,
                             float* __restrict__ out)
{
  int t = blockIdx.x;
  int c = threadIdx.x * 4;
  int p0 = pair_idx[t * 2], p1 = pair_idx[t * 2 + 1];
  float w0 = wsel[t * 2], w1 = wsel[t * 2 + 1];
  float4 a = *(const float4*)(hattn + (size_t)t * 1024 + c);
  float y0[4] = {0.f, 0.f, 0.f, 0.f};
  float y1[4] = {0.f, 0.f, 0.f, 0.f};
  #pragma unroll
  for (int s = 0; s < 4; ++s) {
    const u16* base = y + (size_t)s * 4096 * 1024;
    uint2 v0 = *(const uint2*)(base + (size_t)p0 * 1024 + c);
    uint2 v1 = *(const uint2*)(base + (size_t)p1 * 1024 + c);
    y0[0] += bf2f((u16)(v0.x & 0xffff)); y0[1] += bf2f((u16)(v0.x >> 16));
    y0[2] += bf2f((u16)(v0.y & 0xffff)); y0[3] += bf2f((u16)(v0.y >> 16));
    y1[0] += bf2f((u16)(v1.x & 0xffff)); y1[1] += bf2f((u16)(v1.x >> 16));
    y1[2] += bf2f((u16)(v1.y & 0xffff)); y1[3] += bf2f((u16)(v1.y >> 16));
  }
  float4 r;
  r.x = a.x + w0 * y0[0] + w1 * y1[0];
  r.y = a.y + w0 * y0[1] + w1 * y1[1];
  r.z = a.z + w0 * y0[2] + w1 * y1[2];
  r.w = a.w + w0 * y0[3] + w1 * y1[3];
  *(float4*)(out + (size_t)t * 1024 + c) = r;
}

extern "C" void kernel_launch(void* const* d_in, const int* in_sizes, int n_in,
                              void* d_out, int out_size, void* d_ws, size_t ws_size,
                              hipStream_t stream)
{
  const float* hidden   = (const float*)d_in[0];
  const float* ln1_w    = (const float*)d_in[1];
  const float* ln1_b    = (const float*)d_in[2];
  const float* ln2_w    = (const float*)d_in[3];
  const float* ln2_b    = (const float*)d_in[4];
  const float* qkv_w    = (const float*)d_in[5];
  const float* proj_w   = (const float*)d_in[6];
  const float* router_w = (const float*)d_in[7];
  const float* moe_w1   = (const float*)d_in[8];
  const float* moe_w2   = (const float*)d_in[9];
  float* out = (float*)d_out;

  char* ws = (char*)d_ws;
  size_t off = 0;
  auto alloc = [&](size_t bytes) -> void* {
    void* p = (void*)(ws + off);
    off += (bytes + 255) & ~(size_t)255;
    return p;
  };

  // ---- long-lived buffers ----
  u16* wT      = (u16*)alloc(8ull * 4096 * 1024 * 2);   // w1t then w2t (64 MB)
  float* hattn = (float*)alloc(2048ull * 1024 * 4);     // 8 MB
  u16* x_hi    = (u16*)alloc(2048ull * 1024 * 2);       // 4 MB
  u16* act     = (u16*)alloc(4096ull * 4096 * 2);       // 32 MB
  u16* ybuf    = (u16*)alloc(4ull * 4096 * 1024 * 4);   // 32 MB used; 64 MB reserved (overlay)

  // ---- short-lived buffers overlaid INSIDE ybuf (dead before fc2 writes it) ----
  char* ov = (char*)ybuf;
  size_t oo = 0;
  auto oalloc = [&](size_t bytes) -> void* {
    void* p = (void*)(ov + oo);
    oo += (bytes + 255) & ~(size_t)255;
    return p;
  };
  u16* ln1_hi  = (u16*)oalloc(2048ull * 1024 * 2);
  u16* ln1_lo  = (u16*)oalloc(2048ull * 1024 * 2);
  u16* qw_hi   = (u16*)oalloc(1536ull * 1024 * 2);
  u16* qw_lo   = (u16*)oalloc(1536ull * 1024 * 2);
  u16* pw_hi   = (u16*)oalloc(1024ull * 1024 * 2);
  u16* pw_lo   = (u16*)oalloc(1024ull * 1024 * 2);
  u16* qkv_hi  = (u16*)oalloc(2048ull * 1536 * 2);
  u16* qkv_lo  = (u16*)oalloc(2048ull * 1536 * 2);
  u16* vt_hi   = (u16*)oalloc(4ull * 64 * 2048 * 2);
  u16* vt_lo   = (u16*)oalloc(4ull * 64 * 2048 * 2);
  u16* at_hi   = (u16*)oalloc(2048ull * 1024 * 2);
  u16* at_lo   = (u16*)oalloc(2048ull * 1024 * 2);
  float* x_f32 = (float*)oalloc(2048ull * 1024 * 4);
  float* part_o  = (float*)oalloc(512ull * 4096 * 4);
  float* part_ml = (float*)oalloc(512ull * 128 * 4);

  // ---- small control buffers ----
  int* counts  = (int*)alloc(8 * 4);
  int* prefix  = (int*)alloc(8 * 4);
  int* esel    = (int*)alloc(2048ull * 2 * 4);
  int* slotsel = (int*)alloc(2048ull * 2 * 4);
  int* topair  = (int*)alloc(4096ull * 4);
  int* pairidx = (int*)alloc(2048ull * 2 * 4);
  float* wsel  = (float*)alloc(2048ull * 2 * 4);

  hipMemsetAsync(counts, 0, 8 * 4, stream);

  ln_kernel<true, false><<<2048, 256, 0, stream>>>(hidden, ln1_w, ln1_b, ln1_hi, ln1_lo, nullptr);

  convert_split_kernel<<<1536, 256, 0, stream>>>(qkv_w, qw_hi, qw_lo, 1536 * 1024 / 4);
  convert_split_kernel<<<1024, 256, 0, stream>>>(proj_w, pw_hi, pw_lo, 1024 * 1024 / 4);

  gemm_kernel<0><<<dim3(12, 16, 1), 256, 0, stream>>>(
      ln1_hi, ln1_lo, qw_hi, qw_lo, 1536, 1024,
      qkv_hi, qkv_lo, nullptr, nullptr, nullptr, nullptr, nullptr);

  vtrans_kernel<<<dim3(64, 2, 4), dim3(32, 8), 0, stream>>>(qkv_hi, vt_hi);
  vtrans_kernel<<<dim3(64, 2, 4), dim3(32, 8), 0, stream>>>(qkv_lo, vt_lo);

  attn_kernel<<<768, 256, 0, stream>>>(qkv_hi, qkv_lo, vt_hi, vt_lo, at_hi, at_lo, part_o, part_ml);
  attn_combine<<<256, 256, 0, stream>>>(part_o, part_ml, at_hi, at_lo);

  gemm_kernel<1><<<dim3(8, 16, 1), 256, 0, stream>>>(
      at_hi, at_lo, pw_hi, pw_lo, 1024, 1024,
      nullptr, nullptr, hattn, hidden, nullptr, nullptr, nullptr);

  ln_kernel<false, true><<<2048, 256, 0, stream>>>(hattn, ln2_w, ln2_b, x_hi, nullptr, x_f32);

  router_kernel<<<2048, 64, 0, stream>>>(x_f32, router_w, counts, esel, slotsel, wsel);
  build_lists_kernel<<<1, 256, 0, stream>>>(counts, prefix, esel, slotsel, topair, pairidx);

  transpose_convert_kernel<<<dim3(64, 16, 8), 256, 0, stream>>>(moe_w1, wT, 1024, 4096);

  gemm_kernel<2><<<dim3(32, 16, 8), 256, 0, stream>>>(
      x_hi, nullptr, wT, nullptr, 4096, 1024,
      act, nullptr, nullptr, nullptr, topair, counts, prefix);

  transpose_convert_kernel<<<dim3(16, 64, 8), 256, 0, stream>>>(moe_w2, wT, 4096, 1024);

  gemm_kernel<3><<<dim3(32, 16, 8), 256, 0, stream>>>(
      act, nullptr, wT, nullptr, 1024, 4096,
      ybuf, nullptr, nullptr, nullptr, topair, counts, prefix);

  final_kernel<<<2048, 256, 0, stream>>>(hattn, ybuf, pairidx, wsel, out);
}